// Round 1
// baseline (4923.711 us; speedup 1.0000x reference)
//
#include <hip/hip_runtime.h>

// Problem constants (fixed by setup_inputs()).
constexpr int B = 2;
constexpr int H = 1080;
constexpr int W = 1920;
constexpr int HW = H * W;              // 2,073,600
// d_out layout (floats): fused [B,6,H,W] at 0, warped_img1 [B,3,H,W] at 12*HW,
// warped_img0 [B,3,H,W] at 18*HW. Total 24*HW.
// d_ws layout (floats): norm for warp(img0) at [ (0*B+b)*HW ], warp(img1) at [ (1*B+b)*HW ].

__global__ __launch_bounds__(256) void splat_kernel(
    const float* __restrict__ img0,
    const float* __restrict__ img1,
    const float* __restrict__ flow,   // [B,4,H,W]
    float* __restrict__ out,          // accumulators live at out+12*HW / out+18*HW
    float* __restrict__ norm)         // [2,B,HW]
{
    int t = blockIdx.x * blockDim.x + threadIdx.x;
    const int NP = B * HW;            // threads per image
    if (t >= 2 * NP) return;
    int i = t / NP;                   // image index: 0 -> img0, 1 -> img1
    int r = t - i * NP;
    int b = r / HW;
    int p = r - b * HW;
    int x = p % W;
    int y = p / W;

    const float* img = i ? img1 : img0;
    // flow channels: img0 uses ch 0,1; img1 uses ch 2,3. Both scaled by 0.5.
    const float* fl = flow + ((size_t)b * 4 + (i ? 2 : 0)) * HW;
    float fx = fl[p] * 0.5f;
    float fy = fl[HW + p] * 0.5f;

    float fltX = (float)x + fx;
    float fltY = (float)y + fy;
    float x0f = floorf(fltX);
    float y0f = floorf(fltY);
    int x0 = (int)x0f;
    int y0 = (int)y0f;
    float ax = fltX - x0f;            // in [0,1)
    float ay = fltY - y0f;
    float bx = 1.0f - ax;
    float by = 1.0f - ay;
    float w00 = bx * by;
    float w10 = ax * by;
    float w01 = bx * ay;
    float w11 = ax * ay;

    // source pixel values (3 channels)
    size_t ib = (size_t)b * 3 * HW + p;
    float v0 = img[ib];
    float v1 = img[ib + HW];
    float v2 = img[ib + 2 * (size_t)HW];

    // destination region: image1 -> warped_img1 @ 12*HW, image0 -> warped_img0 @ 18*HW
    float* dst = out + (size_t)HW * (i ? 12 : 18) + (size_t)b * 3 * HW;
    float* nrm = norm + ((size_t)i * B + b) * HW;

    int xs[4] = { x0, x0 + 1, x0,     x0 + 1 };
    int ys[4] = { y0, y0,     y0 + 1, y0 + 1 };
    float ww[4] = { w00, w10, w01, w11 };
#pragma unroll
    for (int k = 0; k < 4; ++k) {
        int xx = xs[k], yy = ys[k];
        if (xx >= 0 && xx < W && yy >= 0 && yy < H) {
            int q = yy * W + xx;
            float w = ww[k];
            atomicAdd(dst + q, v0 * w);
            atomicAdd(dst + HW + q, v1 * w);
            atomicAdd(dst + 2 * (size_t)HW + q, v2 * w);
            atomicAdd(nrm + q, w);
        }
    }
}

__global__ __launch_bounds__(256) void fuse_kernel(
    const float* __restrict__ img0,
    const float* __restrict__ img1,
    float* __restrict__ out,
    const float* __restrict__ norm)
{
    int t = blockIdx.x * blockDim.x + threadIdx.x;
    if (t >= B * HW) return;
    int b = t / HW;
    int p = t - b * HW;

    float n0 = norm[((size_t)0 * B + b) * HW + p];
    float n1 = norm[((size_t)1 * B + b) * HW + p];
    if (n0 == 0.0f) n0 = 1.0f;
    if (n1 == 0.0f) n1 = 1.0f;

    size_t cb = (size_t)b * 3 * HW + p;      // channel-base within a [B,3,H,W] region
#pragma unroll
    for (int c = 0; c < 3; ++c) {
        size_t o = cb + (size_t)c * HW;
        float a1 = out[12 * (size_t)HW + o] / n1;
        float a0 = out[18 * (size_t)HW + o] / n0;
        out[12 * (size_t)HW + o] = a1;       // warped_img1 (normalized)
        out[18 * (size_t)HW + o] = a0;       // warped_img0 (normalized)
        // fused: [B,6,H,W] — channels 0..2 = w1-w0, 3..5 = img1-img0
        size_t f = ((size_t)b * 6 + c) * HW + p;
        out[f] = a1 - a0;
        out[f + 3 * (size_t)HW] = img1[o] - img0[o];
    }
}

extern "C" void kernel_launch(void* const* d_in, const int* in_sizes, int n_in,
                              void* d_out, int out_size, void* d_ws, size_t ws_size,
                              hipStream_t stream) {
    const float* img0 = (const float*)d_in[0];
    const float* img1 = (const float*)d_in[1];
    const float* flow = (const float*)d_in[2];
    float* out = (float*)d_out;
    float* norm = (float*)d_ws;

    // Zero the accumulator regions: warped_img1+warped_img0 (12*HW floats) and norms (4*HW floats).
    hipMemsetAsync(out + 12 * (size_t)HW, 0, 12 * (size_t)HW * sizeof(float), stream);
    hipMemsetAsync(norm, 0, 4 * (size_t)HW * sizeof(float), stream);

    {
        int total = 2 * B * HW;
        int threads = 256;
        int blocks = (total + threads - 1) / threads;
        splat_kernel<<<blocks, threads, 0, stream>>>(img0, img1, flow, out, norm);
    }
    {
        int total = B * HW;
        int threads = 256;
        int blocks = (total + threads - 1) / threads;
        fuse_kernel<<<blocks, threads, 0, stream>>>(img0, img1, out, norm);
    }
}

// Round 2
// 1056.118 us; speedup vs baseline: 4.6621x; 4.6621x over previous
//
#include <hip/hip_runtime.h>

// Problem constants (fixed by setup_inputs()).
constexpr int B = 2;
constexpr int H = 1080;
constexpr int W = 1920;
constexpr int HW = H * W;              // 2,073,600
// d_out layout (floats): fused [B,6,H,W] at 0, warped_img1 [B,3,H,W] at 12*HW,
// warped_img0 [B,3,H,W] at 18*HW. Total 24*HW.
// d_ws layout (floats): norm accumulators [2 images][B][HW] = 4*HW floats.

// Tiling for the LDS-privatized scatter.
constexpr int TW = 128, TH = 32;       // source tile
constexpr int R  = 11;                 // halo radius; P(|N(0,5)| > 11) ~ 1.4% per side,
                                       // but only pixels near the tile edge can spill -> ~0.2% corners
constexpr int HALO_W = TW + 2 * R;     // 150
constexpr int HALO_H = TH + 2 * R;     // 54
constexpr int NCELL  = HALO_W * HALO_H; // 8100 cells; 2 floats/cell = 63.3 KiB LDS
constexpr int NTX = W / TW;            // 15 (exact)
constexpr int NTY = (H + TH - 1) / TH; // 34 (last tile is 8 rows)

__global__ __launch_bounds__(256) void splat_tiled(
    const float* __restrict__ img0,
    const float* __restrict__ img1,
    const float* __restrict__ flow,   // [B,4,H,W]
    float* __restrict__ out,
    float* __restrict__ norm)
{
    __shared__ float sA[NCELL];
    __shared__ float sB[NCELL];

    int bid = blockIdx.x;
    int i = bid / (B * NTX * NTY);          // image index
    int r = bid - i * (B * NTX * NTY);
    int b = r / (NTX * NTY);
    int t = r - b * (NTX * NTY);
    int ty0 = (t / NTX) * TH;
    int tx0 = (t - (t / NTX) * NTX) * TW;
    int tid = threadIdx.x;

    const float* img = i ? img1 : img0;
    const float* flx = flow + ((size_t)b * 4 + (i ? 2 : 0)) * HW;
    const float* fly = flx + HW;
    // image1 -> warped_img1 @ 12*HW, image0 -> warped_img0 @ 18*HW
    float* dst = out + (size_t)HW * (i ? 12 : 18) + (size_t)b * 3 * HW;
    float* nrm = norm + ((size_t)i * B + b) * HW;

    const float* imgb = img + (size_t)b * 3 * HW;

    for (int ph = 0; ph < 2; ++ph) {
        // zero LDS accumulators
        for (int c = tid; c < NCELL; c += 256) { sA[c] = 0.f; sB[c] = 0.f; }
        __syncthreads();

        const float* pa = imgb + (size_t)(ph ? 2 : 0) * HW;   // ch0 or ch2
        const float* pb = imgb + (size_t)HW;                  // ch1 (phase 0 only)
        float* ga = dst + (size_t)(ph ? 2 : 0) * HW;          // global plane for A
        float* gb = ph ? nrm : dst + HW;                      // global plane for B

        // scatter source pixels of this tile
        for (int q = tid; q < TW * TH; q += 256) {
            int lx = q & (TW - 1);
            int ly = q >> 7;                 // TW == 128
            int gx = tx0 + lx, gy = ty0 + ly;
            if (gy >= H) break;              // q monotonic -> all later rows also out
            int p = gy * W + gx;
            float fx = flx[p] * 0.5f;
            float fy = fly[p] * 0.5f;
            float fltX = (float)gx + fx;
            float fltY = (float)gy + fy;
            float x0f = floorf(fltX), y0f = floorf(fltY);
            int x0 = (int)x0f, y0 = (int)y0f;
            float ax = fltX - x0f, ay = fltY - y0f;
            float bx = 1.f - ax, by = 1.f - ay;
            float va = pa[p];
            float vb = ph ? 1.f : pb[p];
            int hx = x0 - (tx0 - R);
            int hy = y0 - (ty0 - R);
            float wgt[4] = { bx * by, ax * by, bx * ay, ax * ay };
#pragma unroll
            for (int k = 0; k < 4; ++k) {
                int dxk = k & 1, dyk = k >> 1;
                int hxx = hx + dxk, hyy = hy + dyk;
                float w = wgt[k];
                if ((unsigned)hxx < (unsigned)HALO_W && (unsigned)hyy < (unsigned)HALO_H) {
                    int cell = hyy * HALO_W + hxx;
                    atomicAdd(&sA[cell], va * w);
                    atomicAdd(&sB[cell], vb * w);
                } else {
                    int xx = x0 + dxk, yy = y0 + dyk;
                    if ((unsigned)xx < (unsigned)W && (unsigned)yy < (unsigned)H) {
                        int g = yy * W + xx;
                        atomicAdd(ga + g, va * w);
                        atomicAdd(gb + g, vb * w);
                    }
                }
            }
        }
        __syncthreads();

        // merge halo tile into global planes (coalesced atomics, skip zeros)
        for (int c = tid; c < NCELL; c += 256) {
            float a = sA[c], bb = sB[c];
            if (a != 0.f || bb != 0.f) {
                int hy = c / HALO_W;
                int hx = c - hy * HALO_W;
                int gx = tx0 - R + hx;
                int gy = ty0 - R + hy;
                if ((unsigned)gx < (unsigned)W && (unsigned)gy < (unsigned)H) {
                    int g = gy * W + gx;
                    atomicAdd(ga + g, a);
                    atomicAdd(gb + g, bb);
                }
            }
        }
        __syncthreads();
    }
}

__global__ __launch_bounds__(256) void fuse_kernel(
    const float* __restrict__ img0,
    const float* __restrict__ img1,
    float* __restrict__ out,
    const float* __restrict__ norm)
{
    int t = blockIdx.x * blockDim.x + threadIdx.x;
    const int NP4 = HW / 4;                  // HW divisible by 4
    if (t >= B * NP4) return;
    int b = t / NP4;
    int p4 = t - b * NP4;                    // float4 index within plane

    const float4* n0p = (const float4*)(norm + ((size_t)0 * B + b) * HW);
    const float4* n1p = (const float4*)(norm + ((size_t)1 * B + b) * HW);
    float4 n0 = n0p[p4];
    float4 n1 = n1p[p4];
    n0.x = n0.x == 0.f ? 1.f : n0.x;  n0.y = n0.y == 0.f ? 1.f : n0.y;
    n0.z = n0.z == 0.f ? 1.f : n0.z;  n0.w = n0.w == 0.f ? 1.f : n0.w;
    n1.x = n1.x == 0.f ? 1.f : n1.x;  n1.y = n1.y == 0.f ? 1.f : n1.y;
    n1.z = n1.z == 0.f ? 1.f : n1.z;  n1.w = n1.w == 0.f ? 1.f : n1.w;

    size_t cb4 = (size_t)b * 3 * (HW / 4) + p4;   // channel-base (in float4 units) within [B,3,H,W]
#pragma unroll
    for (int c = 0; c < 3; ++c) {
        size_t o = cb4 + (size_t)c * (HW / 4);
        float4 a1 = ((const float4*)(out + 12 * (size_t)HW))[o];
        float4 a0 = ((const float4*)(out + 18 * (size_t)HW))[o];
        a1.x /= n1.x; a1.y /= n1.y; a1.z /= n1.z; a1.w /= n1.w;
        a0.x /= n0.x; a0.y /= n0.y; a0.z /= n0.z; a0.w /= n0.w;
        ((float4*)(out + 12 * (size_t)HW))[o] = a1;   // warped_img1 normalized
        ((float4*)(out + 18 * (size_t)HW))[o] = a0;   // warped_img0 normalized
        float4 d; d.x = a1.x - a0.x; d.y = a1.y - a0.y; d.z = a1.z - a0.z; d.w = a1.w - a0.w;
        size_t f = ((size_t)b * 6 + c) * (HW / 4) + p4;
        ((float4*)out)[f] = d;                         // fused ch 0..2
        float4 i0 = ((const float4*)img0)[o];
        float4 i1 = ((const float4*)img1)[o];
        float4 e; e.x = i1.x - i0.x; e.y = i1.y - i0.y; e.z = i1.z - i0.z; e.w = i1.w - i0.w;
        ((float4*)out)[f + 3 * (size_t)(HW / 4)] = e;  // fused ch 3..5
    }
}

extern "C" void kernel_launch(void* const* d_in, const int* in_sizes, int n_in,
                              void* d_out, int out_size, void* d_ws, size_t ws_size,
                              hipStream_t stream) {
    const float* img0 = (const float*)d_in[0];
    const float* img1 = (const float*)d_in[1];
    const float* flow = (const float*)d_in[2];
    float* out = (float*)d_out;
    float* norm = (float*)d_ws;

    // Zero accumulator regions: warped planes (12*HW floats) and norms (4*HW floats).
    hipMemsetAsync(out + 12 * (size_t)HW, 0, 12 * (size_t)HW * sizeof(float), stream);
    hipMemsetAsync(norm, 0, 4 * (size_t)HW * sizeof(float), stream);

    {
        int blocks = 2 * B * NTX * NTY;     // 2040
        splat_tiled<<<blocks, 256, 0, stream>>>(img0, img1, flow, out, norm);
    }
    {
        int total = B * (HW / 4);
        int blocks = (total + 255) / 256;
        fuse_kernel<<<blocks, 256, 0, stream>>>(img0, img1, out, norm);
    }
}

// Round 3
// 1021.776 us; speedup vs baseline: 4.8188x; 1.0336x over previous
//
#include <hip/hip_runtime.h>

// Problem constants (fixed by setup_inputs()).
constexpr int B = 2;
constexpr int H = 1080;
constexpr int W = 1920;
constexpr int HW = H * W;              // 2,073,600
// d_out layout (floats): fused [B,6,H,W] at 0, warped_img1 [B,3,H,W] at 12*HW,
// warped_img0 [B,3,H,W] at 18*HW. Total 24*HW.
// d_ws layout (floats): norm accumulators [2 images][B][HW] = 4*HW floats.

// Tiling: 96x32 source tile, R=11 halo -> 118x54 = 6372 cells * 2 planes * 4B = 49.8 KiB LDS
// -> 3 blocks/CU (12 waves) vs round-2's 2 blocks (8 waves).
constexpr int TW = 96, TH = 32;
constexpr int R  = 11;
constexpr int HALO_W = TW + 2 * R;       // 118
constexpr int HALO_H = TH + 2 * R;       // 54
constexpr int NCELL  = HALO_W * HALO_H;  // 6372
constexpr int NTX = (W + TW - 1) / TW;   // 20 (exact)
constexpr int NTY = (H + TH - 1) / TH;   // 34 (last tile 24 rows)
constexpr int NTILES = NTX * NTY;        // 680

__device__ __forceinline__ void fadd(float* p, float v) {
    // guarantees native ds_add_f32 / global_atomic_add_f32 (no CAS loop)
    unsafeAtomicAdd(p, v);
}

__global__ __launch_bounds__(256, 3) void splat_tiled(
    const float* __restrict__ img0,
    const float* __restrict__ img1,
    const float* __restrict__ flow,   // [B,4,H,W]
    float* __restrict__ out,
    float* __restrict__ norm)
{
    __shared__ float sA[NCELL];
    __shared__ float sB[NCELL];

    int bid = blockIdx.x;
    int t   = bid % NTILES;
    int r   = bid / NTILES;            // ((i*B + b)*2 + ph)
    int ph  = r & 1;
    int ib  = r >> 1;
    int b   = ib & 1;                  // B == 2
    int i   = ib >> 1;                 // image index
    int ty0 = (t / NTX) * TH;
    int tx0 = (t - (t / NTX) * NTX) * TW;
    int tid = threadIdx.x;

    const float* img = i ? img1 : img0;
    const float* flx = flow + ((size_t)b * 4 + (i ? 2 : 0)) * HW;
    const float* fly = flx + HW;
    float* dst = out + (size_t)HW * (i ? 12 : 18) + (size_t)b * 3 * HW;
    float* nrm = norm + ((size_t)i * B + b) * HW;
    const float* imgb = img + (size_t)b * 3 * HW;

    // phase 0: planes (ch0, ch1); phase 1: planes (ch2, norm)
    const float* pa = imgb + (size_t)(ph ? 2 : 0) * HW;
    const float* pb = imgb + (size_t)HW;
    float* ga = dst + (size_t)(ph ? 2 : 0) * HW;
    float* gb = ph ? nrm : dst + HW;

    // zero LDS accumulators
    for (int c = tid; c < NCELL; c += 256) { sA[c] = 0.f; sB[c] = 0.f; }
    __syncthreads();

    // scatter: 4 consecutive pixels per thread-iteration (float4 loads)
    constexpr int GPR = TW / 4;              // 24 float4-groups per row
    constexpr int NGRP = TW * TH / 4;        // 768 groups -> 3 iters of 256 threads
    for (int g = tid; g < NGRP; g += 256) {
        int row = g / GPR;
        int col = (g - row * GPR) * 4;
        int gy = ty0 + row;
        if (gy >= H) break;                  // g monotonic -> later rows also out
        int gx0 = tx0 + col;
        int p = gy * W + gx0;
        float4 fx4 = *(const float4*)(flx + p);
        float4 fy4 = *(const float4*)(fly + p);
        float4 va4 = *(const float4*)(pa + p);
        float4 vb4;
        if (ph) { vb4 = make_float4(1.f, 1.f, 1.f, 1.f); }
        else    { vb4 = *(const float4*)(pb + p); }

#pragma unroll
        for (int j = 0; j < 4; ++j) {
            float fx = (&fx4.x)[j] * 0.5f;
            float fy = (&fy4.x)[j] * 0.5f;
            float va = (&va4.x)[j];
            float vb = (&vb4.x)[j];
            float fltX = (float)(gx0 + j) + fx;
            float fltY = (float)gy + fy;
            float x0f = floorf(fltX), y0f = floorf(fltY);
            int x0 = (int)x0f, y0 = (int)y0f;
            float ax = fltX - x0f, ay = fltY - y0f;
            float bx = 1.f - ax, by = 1.f - ay;
            int hx = x0 - (tx0 - R);
            int hy = y0 - (ty0 - R);
            float wgt[4] = { bx * by, ax * by, bx * ay, ax * ay };
#pragma unroll
            for (int k = 0; k < 4; ++k) {
                int dxk = k & 1, dyk = k >> 1;
                int hxx = hx + dxk, hyy = hy + dyk;
                float w = wgt[k];
                if ((unsigned)hxx < (unsigned)HALO_W && (unsigned)hyy < (unsigned)HALO_H) {
                    int cell = hyy * HALO_W + hxx;
                    fadd(&sA[cell], va * w);
                    fadd(&sB[cell], vb * w);
                } else {
                    int xx = x0 + dxk, yy = y0 + dyk;
                    if ((unsigned)xx < (unsigned)W && (unsigned)yy < (unsigned)H) {
                        int gq = yy * W + xx;
                        fadd(ga + gq, va * w);
                        fadd(gb + gq, vb * w);
                    }
                }
            }
        }
    }
    __syncthreads();

    // merge halo tile into global planes (coalesced atomics, skip zeros)
    for (int c = tid; c < NCELL; c += 256) {
        float a = sA[c], bb = sB[c];
        if (a != 0.f || bb != 0.f) {
            int hy = c / HALO_W;
            int hx = c - hy * HALO_W;
            int gx = tx0 - R + hx;
            int gy = ty0 - R + hy;
            if ((unsigned)gx < (unsigned)W && (unsigned)gy < (unsigned)H) {
                int gq = gy * W + gx;
                fadd(ga + gq, a);
                fadd(gb + gq, bb);
            }
        }
    }
}

__global__ __launch_bounds__(256) void fuse_kernel(
    const float* __restrict__ img0,
    const float* __restrict__ img1,
    float* __restrict__ out,
    const float* __restrict__ norm)
{
    int t = blockIdx.x * blockDim.x + threadIdx.x;
    const int NP4 = HW / 4;
    if (t >= B * NP4) return;
    int b = t / NP4;
    int p4 = t - b * NP4;

    float4 n0 = ((const float4*)(norm + ((size_t)0 * B + b) * HW))[p4];
    float4 n1 = ((const float4*)(norm + ((size_t)1 * B + b) * HW))[p4];
    n0.x = n0.x == 0.f ? 1.f : n0.x;  n0.y = n0.y == 0.f ? 1.f : n0.y;
    n0.z = n0.z == 0.f ? 1.f : n0.z;  n0.w = n0.w == 0.f ? 1.f : n0.w;
    n1.x = n1.x == 0.f ? 1.f : n1.x;  n1.y = n1.y == 0.f ? 1.f : n1.y;
    n1.z = n1.z == 0.f ? 1.f : n1.z;  n1.w = n1.w == 0.f ? 1.f : n1.w;

    size_t cb4 = (size_t)b * 3 * (HW / 4) + p4;
#pragma unroll
    for (int c = 0; c < 3; ++c) {
        size_t o = cb4 + (size_t)c * (HW / 4);
        float4 a1 = ((const float4*)(out + 12 * (size_t)HW))[o];
        float4 a0 = ((const float4*)(out + 18 * (size_t)HW))[o];
        a1.x /= n1.x; a1.y /= n1.y; a1.z /= n1.z; a1.w /= n1.w;
        a0.x /= n0.x; a0.y /= n0.y; a0.z /= n0.z; a0.w /= n0.w;
        ((float4*)(out + 12 * (size_t)HW))[o] = a1;
        ((float4*)(out + 18 * (size_t)HW))[o] = a0;
        float4 d; d.x = a1.x - a0.x; d.y = a1.y - a0.y; d.z = a1.z - a0.z; d.w = a1.w - a0.w;
        size_t f = ((size_t)b * 6 + c) * (HW / 4) + p4;
        ((float4*)out)[f] = d;
        float4 i0 = ((const float4*)img0)[o];
        float4 i1 = ((const float4*)img1)[o];
        float4 e; e.x = i1.x - i0.x; e.y = i1.y - i0.y; e.z = i1.z - i0.z; e.w = i1.w - i0.w;
        ((float4*)out)[f + 3 * (size_t)(HW / 4)] = e;
    }
}

extern "C" void kernel_launch(void* const* d_in, const int* in_sizes, int n_in,
                              void* d_out, int out_size, void* d_ws, size_t ws_size,
                              hipStream_t stream) {
    const float* img0 = (const float*)d_in[0];
    const float* img1 = (const float*)d_in[1];
    const float* flow = (const float*)d_in[2];
    float* out = (float*)d_out;
    float* norm = (float*)d_ws;

    hipMemsetAsync(out + 12 * (size_t)HW, 0, 12 * (size_t)HW * sizeof(float), stream);
    hipMemsetAsync(norm, 0, 4 * (size_t)HW * sizeof(float), stream);

    {
        int blocks = 2 * B * 2 * NTILES;     // img x batch x phase x tiles = 5440
        splat_tiled<<<blocks, 256, 0, stream>>>(img0, img1, flow, out, norm);
    }
    {
        int total = B * (HW / 4);
        int blocks = (total + 255) / 256;
        fuse_kernel<<<blocks, 256, 0, stream>>>(img0, img1, out, norm);
    }
}